// Round 1
// baseline (508.592 us; speedup 1.0000x reference)
//
#include <hip/hip_runtime.h>
#include <hip/hip_bf16.h>

#define NN 20000
#define EE 640000

// ---------------- CSR build ----------------

__global__ void init_cnt_kernel(int* __restrict__ cnt, int n) {
    int i = blockIdx.x * 256 + threadIdx.x;
    if (i < n) cnt[i] = 0;
}

__global__ void hist_kernel(const int* __restrict__ col, int* __restrict__ cnt, int e) {
    int i = blockIdx.x * 256 + threadIdx.x;
    if (i < e) atomicAdd(&cnt[col[i]], 1);
}

__global__ void dinv_kernel(const int* __restrict__ cnt, float* __restrict__ dinv, int n) {
    int i = blockIdx.x * 256 + threadIdx.x;
    if (i < n) dinv[i] = rsqrtf((float)(cnt[i] + 1));  // +1 self-loop; always > 0
}

// single-block exclusive scan over n counts -> offs, cursor
__global__ void scan_kernel(const int* __restrict__ cnt, int* __restrict__ offs,
                            int* __restrict__ cursor, int n) {
    __shared__ int wsum[4];
    __shared__ int carry;
    int tid = threadIdx.x;
    int lane = tid & 63, w = tid >> 6;
    if (tid == 0) carry = 0;
    __syncthreads();
    for (int base = 0; base < n; base += 256) {
        int i = base + tid;
        int v = (i < n) ? cnt[i] : 0;
        int x = v;
        #pragma unroll
        for (int d = 1; d < 64; d <<= 1) {
            int y = __shfl_up(x, d, 64);
            if (lane >= d) x += y;
        }
        if (lane == 63) wsum[w] = x;
        __syncthreads();
        if (tid == 0) {
            int s = 0;
            #pragma unroll
            for (int k = 0; k < 4; ++k) { int t = wsum[k]; wsum[k] = s; s += t; }
        }
        __syncthreads();
        int excl = carry + wsum[w] + x - v;
        if (i < n) { offs[i] = excl; cursor[i] = excl; }
        __syncthreads();
        if (tid == 255) carry += wsum[3] + x;
        __syncthreads();
    }
}

__global__ void scatter_kernel(const int* __restrict__ row, const int* __restrict__ col,
                               const float* __restrict__ dinv, int* __restrict__ cursor,
                               int* __restrict__ csr_src, float* __restrict__ csr_nrm, int e) {
    int i = blockIdx.x * 256 + threadIdx.x;
    if (i >= e) return;
    int s = row[i], d = col[i];
    int pos = atomicAdd(&cursor[d], 1);
    csr_src[pos] = s;
    csr_nrm[pos] = dinv[s] * dinv[d];
}

// ---------------- aggregation: out[i] = dinv[i]^2*h[i] + sum_e nrm*h[src] ----------------
// 4 nodes per 256-thread block, one wave (64 lanes * float4 = 256 feats) per node.
__global__ __launch_bounds__(256) void agg_kernel(
    const float* __restrict__ h,
    const int* __restrict__ offs, const int* __restrict__ cnt,
    const int* __restrict__ csr_src, const float* __restrict__ csr_nrm,
    const float* __restrict__ dinv,
    float* __restrict__ out, int n) {
    int node = blockIdx.x * 4 + (threadIdx.x >> 6);
    int lane = threadIdx.x & 63;
    if (node >= n) return;
    float di = dinv[node];
    float sn = di * di;
    float4 hv = ((const float4*)(h + (size_t)node * 256))[lane];
    float4 acc = { sn * hv.x, sn * hv.y, sn * hv.z, sn * hv.w };
    int beg = offs[node];
    int num = cnt[node];
    int j = 0;
    for (; j + 1 < num; j += 2) {
        int   s0 = csr_src[beg + j],     s1 = csr_src[beg + j + 1];
        float m0 = csr_nrm[beg + j],     m1 = csr_nrm[beg + j + 1];
        float4 v0 = ((const float4*)(h + (size_t)s0 * 256))[lane];
        float4 v1 = ((const float4*)(h + (size_t)s1 * 256))[lane];
        acc.x = fmaf(m0, v0.x, acc.x); acc.y = fmaf(m0, v0.y, acc.y);
        acc.z = fmaf(m0, v0.z, acc.z); acc.w = fmaf(m0, v0.w, acc.w);
        acc.x = fmaf(m1, v1.x, acc.x); acc.y = fmaf(m1, v1.y, acc.y);
        acc.z = fmaf(m1, v1.z, acc.z); acc.w = fmaf(m1, v1.w, acc.w);
    }
    if (j < num) {
        int   s0 = csr_src[beg + j];
        float m0 = csr_nrm[beg + j];
        float4 v0 = ((const float4*)(h + (size_t)s0 * 256))[lane];
        acc.x = fmaf(m0, v0.x, acc.x); acc.y = fmaf(m0, v0.y, acc.y);
        acc.z = fmaf(m0, v0.z, acc.z); acc.w = fmaf(m0, v0.w, acc.w);
    }
    ((float4*)(out + (size_t)node * 256))[lane] = acc;
}

// ---------------- f32 GEMM: C[n,256] = A[n,256] @ W[256,256] + bias (opt ReLU) ----------------
template<bool RELU>
__global__ __launch_bounds__(256) void gemm_bias_kernel(
    const float* __restrict__ A, const float* __restrict__ W,
    const float* __restrict__ bias, float* __restrict__ C, int n) {
    __shared__ float Ast[32][68];   // [k][row], padded
    __shared__ float Bs[32][64];    // [k][col]
    int tid = threadIdx.x;
    int tx = tid & 15, ty = tid >> 4;
    int m0 = blockIdx.x * 64;
    int n0 = blockIdx.y * 64;
    float acc[4][4] = {};
    for (int k0 = 0; k0 < 256; k0 += 32) {
        // A tile (64 rows x 32 k) -> transposed into LDS
        int s = tid;
        #pragma unroll
        for (int rep = 0; rep < 2; ++rep, s += 256) {
            int r = s >> 3;          // 0..63
            int cg = s & 7;          // 0..7
            int gr = m0 + r; if (gr > n - 1) gr = n - 1;
            float4 a = *(const float4*)(A + (size_t)gr * 256 + k0 + cg * 4);
            Ast[cg * 4 + 0][r] = a.x;
            Ast[cg * 4 + 1][r] = a.y;
            Ast[cg * 4 + 2][r] = a.z;
            Ast[cg * 4 + 3][r] = a.w;
        }
        // W tile (32 k x 64 cols)
        s = tid;
        #pragma unroll
        for (int rep = 0; rep < 2; ++rep, s += 256) {
            int kk = s >> 4;         // 0..31
            int cg = s & 15;         // 0..15
            *(float4*)(&Bs[kk][cg * 4]) =
                *(const float4*)(W + (size_t)(k0 + kk) * 256 + n0 + cg * 4);
        }
        __syncthreads();
        #pragma unroll
        for (int k = 0; k < 32; ++k) {
            float4 av = *(const float4*)(&Ast[k][ty * 4]);
            float4 bv = *(const float4*)(&Bs[k][tx * 4]);
            float a_[4] = { av.x, av.y, av.z, av.w };
            float b_[4] = { bv.x, bv.y, bv.z, bv.w };
            #pragma unroll
            for (int i = 0; i < 4; ++i)
                #pragma unroll
                for (int jj = 0; jj < 4; ++jj)
                    acc[i][jj] = fmaf(a_[i], b_[jj], acc[i][jj]);
        }
        __syncthreads();
    }
    float4 bv = *(const float4*)(bias + n0 + tx * 4);
    int row0 = m0 + ty * 4;
    #pragma unroll
    for (int i = 0; i < 4; ++i) {
        int r = row0 + i;
        if (r < n) {
            float4 o;
            o.x = acc[i][0] + bv.x;
            o.y = acc[i][1] + bv.y;
            o.z = acc[i][2] + bv.z;
            o.w = acc[i][3] + bv.w;
            if (RELU) {
                o.x = fmaxf(o.x, 0.f); o.y = fmaxf(o.y, 0.f);
                o.z = fmaxf(o.z, 0.f); o.w = fmaxf(o.w, 0.f);
            }
            *(float4*)(C + (size_t)r * 256 + n0 + tx * 4) = o;
        }
    }
}

// ---------------- final projection: out[i] = h3[i,:] . Wout + bout ----------------
__global__ __launch_bounds__(256) void out_kernel(
    const float* __restrict__ h3, const float* __restrict__ Wout,
    const float* __restrict__ bout, float* __restrict__ out, int n) {
    int node = blockIdx.x * 4 + (threadIdx.x >> 6);
    int lane = threadIdx.x & 63;
    if (node >= n) return;
    float4 v = ((const float4*)(h3 + (size_t)node * 256))[lane];
    float4 w = ((const float4*)Wout)[lane];
    float sum = v.x * w.x + v.y * w.y + v.z * w.z + v.w * w.w;
    #pragma unroll
    for (int d = 32; d > 0; d >>= 1) sum += __shfl_down(sum, d, 64);
    if (lane == 0) out[node] = sum + bout[0];
}

extern "C" void kernel_launch(void* const* d_in, const int* in_sizes, int n_in,
                              void* d_out, int out_size, void* d_ws, size_t ws_size,
                              hipStream_t stream) {
    const int n = NN, e = EE;
    const float* x    = (const float*)d_in[0];
    const int*   eidx = (const int*)d_in[1];   // int32 per harness convention
    const float* W1   = (const float*)d_in[2];
    const float* b1   = (const float*)d_in[3];
    const float* Wh   = (const float*)d_in[4];
    const float* bh   = (const float*)d_in[5];
    const float* W2   = (const float*)d_in[6];
    const float* b2   = (const float*)d_in[7];
    const float* Wout = (const float*)d_in[8];
    const float* bout = (const float*)d_in[9];
    const int* row = eidx;        // sources
    const int* col = eidx + e;    // destinations

    char* ws = (char*)d_ws;
    int*   cnt     = (int*)ws;    ws += (size_t)n * 4;
    int*   offs    = (int*)ws;    ws += (size_t)n * 4;
    int*   cursor  = (int*)ws;    ws += (size_t)n * 4;
    float* dinv    = (float*)ws;  ws += (size_t)n * 4;
    int*   csr_src = (int*)ws;    ws += (size_t)e * 4;
    float* csr_nrm = (float*)ws;  ws += (size_t)e * 4;
    float* bufA    = (float*)ws;  ws += (size_t)n * 256 * 4;
    float* bufB    = (float*)ws;  ws += (size_t)n * 256 * 4;

    float* outv = (float*)d_out;
    float* h3   = (float*)d_out + n;   // embedding output lives in d_out

    int nb_n = (n + 255) / 256;
    int nb_e = (e + 255) / 256;
    dim3 ggrid((n + 63) / 64, 4);

    // CSR build
    init_cnt_kernel<<<nb_n, 256, 0, stream>>>(cnt, n);
    hist_kernel<<<nb_e, 256, 0, stream>>>(col, cnt, e);
    dinv_kernel<<<nb_n, 256, 0, stream>>>(cnt, dinv, n);
    scan_kernel<<<1, 256, 0, stream>>>(cnt, offs, cursor, n);
    scatter_kernel<<<nb_e, 256, 0, stream>>>(row, col, dinv, cursor, csr_src, csr_nrm, e);

    int agrid = (n + 3) / 4;
    // layer 1: agg(x) -> bufA ; relu(bufA@W1+b1) -> bufB
    agg_kernel<<<agrid, 256, 0, stream>>>(x, offs, cnt, csr_src, csr_nrm, dinv, bufA, n);
    gemm_bias_kernel<true><<<ggrid, 256, 0, stream>>>(bufA, W1, b1, bufB, n);
    // layer 2
    agg_kernel<<<agrid, 256, 0, stream>>>(bufB, offs, cnt, csr_src, csr_nrm, dinv, bufA, n);
    gemm_bias_kernel<true><<<ggrid, 256, 0, stream>>>(bufA, Wh, bh, bufB, n);
    // layer 3 (no relu) -> h3 straight into d_out
    agg_kernel<<<agrid, 256, 0, stream>>>(bufB, offs, cnt, csr_src, csr_nrm, dinv, bufA, n);
    gemm_bias_kernel<false><<<ggrid, 256, 0, stream>>>(bufA, W2, b2, h3, n);
    // decoder
    out_kernel<<<agrid, 256, 0, stream>>>(h3, Wout, bout, outv, n);
}